// Round 1
// baseline (403.529 us; speedup 1.0000x reference)
//
#include <hip/hip_runtime.h>

#define NB    8
#define CIN   128
#define COUT  128
#define HH    32
#define WW    32
#define HO    34
#define WO    34
#define SSP   (HO*WO)     // 1156
#define UU    6
#define NPB   (SSP*UU)    // 6936
#define NPAD  6976        // 109*64
#define EPSC  1e-7f

typedef __attribute__((ext_vector_type(8))) short bf16x8;
typedef __attribute__((ext_vector_type(4))) float f32x4;

__device__ __forceinline__ ushort f2b(float f) {
  uint u = __float_as_uint(f);
  uint r = (u + 0x7fffu + ((u >> 16) & 1u)) >> 16;
  return (ushort)r;
}

// ---------------- prep: G (Cayley) + wT[o][c] = bf16((g[16+c*128+o])^2) ----------------
__global__ void prep_kernel(const float* __restrict__ g,
                            float* __restrict__ G,
                            ushort* __restrict__ wT) {
  if (blockIdx.x == 0) {
    int t = threadIdx.x;
    if (t < 9) {
      const int nums[9] = {0,1,2,3,0,5,6,7,1};
      float a = g[2*nums[t]];
      float c = g[2*nums[t]+1];
      float F[9], S2[9];
      if (t == 4) {
        F[0]=1;F[1]=0;F[2]=0;F[3]=0;F[4]=1;F[5]=0;F[6]=0;F[7]=0;F[8]=1;
        S2[0]=1;S2[1]=0;S2[2]=0;S2[3]=0;S2[4]=1;S2[5]=0;S2[6]=0;S2[7]=0;S2[8]=1;
      } else {
        F[0]=1.f; F[1]=-a;  F[2]=-a;
        F[3]=a;   F[4]=1.f; F[5]=-c;
        F[6]=a;   F[7]=c;   F[8]=1.f;
        S2[0]=1.f;  S2[1]=a;   S2[2]=a;
        S2[3]=-a;   S2[4]=1.f; S2[5]=c;
        S2[6]=-a;   S2[7]=-c;  S2[8]=1.f;
      }
      float det = F[0]*(F[4]*F[8]-F[5]*F[7]) - F[1]*(F[3]*F[8]-F[5]*F[6])
                + F[2]*(F[3]*F[7]-F[4]*F[6]) + EPSC;
      float inv[9];
      inv[0] = (F[4]*F[8]-F[5]*F[7]);
      inv[1] = (F[2]*F[7]-F[1]*F[8]);
      inv[2] = (F[1]*F[5]-F[2]*F[4]);
      inv[3] = (F[5]*F[6]-F[3]*F[8]);
      inv[4] = (F[0]*F[8]-F[2]*F[6]);
      inv[5] = (F[2]*F[3]-F[0]*F[5]);
      inv[6] = (F[3]*F[7]-F[4]*F[6]);
      inv[7] = (F[1]*F[6]-F[0]*F[7]);
      inv[8] = (F[0]*F[4]-F[1]*F[3]);
      float rd = 1.0f/det;
      #pragma unroll
      for (int i = 0; i < 9; ++i) inv[i] *= rd;
      #pragma unroll
      for (int i = 0; i < 3; ++i)
        #pragma unroll
        for (int j = 0; j < 3; ++j)
          G[t*9+i*3+j] = inv[i*3+0]*S2[0*3+j] + inv[i*3+1]*S2[1*3+j] + inv[i*3+2]*S2[2*3+j];
    }
  } else {
    int idx = (int)(blockIdx.x-1)*256 + threadIdx.x;   // 0..16383 ; idx = o*128 + c
    int o = idx >> 7, c = idx & 127;
    float w = g[16 + c*128 + o];
    wT[idx] = f2b(w*w);
  }
}

// ---------------- fold: per (b,c), foldedSym[u][ho][wo] in LDS, write [b][c][s*6+u] bf16 ----------------
__global__ __launch_bounds__(256) void fold_kernel(const float* __restrict__ x,
                                                   const float* __restrict__ Gg,
                                                   ushort* __restrict__ folded) {
  __shared__ float Gs[81];
  __shared__ float fs[UU*HO*36];   // 6*34*36 = 7344 f32
  int tid = threadIdx.x;
  if (tid < 81) Gs[tid] = Gg[tid];
  for (int i = tid; i < UU*HO*36; i += 256) fs[i] = 0.f;
  __syncthreads();

  const int T1[6] = {0,1,2,4,5,8};   // u <-> (i,j): (0,0),(0,1),(0,2),(1,1),(1,2),(2,2)
  const int T2[6] = {0,3,6,4,7,8};
  const float* xb = x + (size_t)blockIdx.x * (HH*WW*9);

  #pragma unroll
  for (int kk = 0; kk < 4; ++kk) {
    int loc = tid + kk*256;          // 0..1023
    int h = loc >> 5, w = loc & 31;
    float X[9];
    #pragma unroll
    for (int i = 0; i < 9; ++i) X[i] = xb[loc*9 + i];

    #pragma unroll
    for (int u = 0; u < 6; ++u) {
      const float* G1 = &Gs[T1[u]*9];
      float W1[9], Y[9];
      #pragma unroll
      for (int i = 0; i < 3; ++i)
        #pragma unroll
        for (int q = 0; q < 3; ++q)
          W1[i*3+q] = G1[i*3+0]*X[0*3+q] + G1[i*3+1]*X[1*3+q] + G1[i*3+2]*X[2*3+q];
      #pragma unroll
      for (int i = 0; i < 3; ++i)
        #pragma unroll
        for (int j = 0; j < 3; ++j)
          Y[i*3+j] = W1[i*3+0]*G1[j*3+0] + W1[i*3+1]*G1[j*3+1] + W1[i*3+2]*G1[j*3+2];
      if (T2[u] != T1[u]) {          // compile-time (u unrolled)
        const float* G2 = &Gs[T2[u]*9];
        float W2[9];
        #pragma unroll
        for (int i = 0; i < 3; ++i)
          #pragma unroll
          for (int q = 0; q < 3; ++q)
            W2[i*3+q] = G2[i*3+0]*X[0*3+q] + G2[i*3+1]*X[1*3+q] + G2[i*3+2]*X[2*3+q];
        #pragma unroll
        for (int i = 0; i < 3; ++i)
          #pragma unroll
          for (int j = 0; j < 3; ++j)
            Y[i*3+j] = 0.5f*(Y[i*3+j] + (W2[i*3+0]*G2[j*3+0] + W2[i*3+1]*G2[j*3+1] + W2[i*3+2]*G2[j*3+2]));
      }
      #pragma unroll
      for (int i = 0; i < 3; ++i)
        #pragma unroll
        for (int j = 0; j < 3; ++j)
          atomicAdd(&fs[(u*HO + h + i)*36 + (w + j)], Y[i*3+j]);
    }
  }
  __syncthreads();

  size_t ob = (size_t)blockIdx.x * NPAD;
  for (int idx = tid; idx < NPAD; idx += 256) {
    ushort v = 0;
    if (idx < NPB) {
      uint s = (uint)idx / 6u;
      int  u = idx - 6*(int)s;
      uint ho = s / 34u;
      uint wo = s - 34u*ho;
      v = f2b(fs[(u*HO + ho)*36 + wo]);
    }
    folded[ob + idx] = v;
  }
}

// ---------------- gemm: mixedSym[o][n] = sum_c wT[o][c] * folded[b][c][n], MFMA bf16 ----------------
__global__ __launch_bounds__(256) void gemm_kernel(const ushort* __restrict__ wT,
                                                   const ushort* __restrict__ folded,
                                                   float* __restrict__ out) {
  __shared__ __align__(16) ushort ldsB[64*136];   // [n_local][k (+8 pad)], XOR-swizzled
  int tid = threadIdx.x;
  int b = blockIdx.y;
  int n0 = (int)blockIdx.x * 64;

  // stage full K=128 x Ntile=64 panel, transposing to [n][k]
  #pragma unroll
  for (int p = 0; p < 4; ++p) {
    int chunk = tid + p*256;              // 0..1023 : c = chunk>>3, n-chunk = (chunk&7)*8
    int c  = chunk >> 3;
    int nc = (chunk & 7) * 8;
    const ushort* src = folded + (size_t)(b*CIN + c)*NPAD + n0 + nc;
    uint4 v = *(const uint4*)src;
    ushort e[8];
    e[0]=(ushort)(v.x & 0xffffu); e[1]=(ushort)(v.x >> 16);
    e[2]=(ushort)(v.y & 0xffffu); e[3]=(ushort)(v.y >> 16);
    e[4]=(ushort)(v.z & 0xffffu); e[5]=(ushort)(v.z >> 16);
    e[6]=(ushort)(v.w & 0xffffu); e[7]=(ushort)(v.w >> 16);
    #pragma unroll
    for (int j = 0; j < 8; ++j) {
      int nl  = nc + j;
      int ksw = c ^ (((nl >> 3) & 7) << 4);
      ldsB[nl*136 + ksw] = e[j];
    }
  }
  __syncthreads();

  int wave = tid >> 6, lane = tid & 63;
  int l15 = lane & 15, lhi = lane >> 4;
  int nl = wave*16 + l15;
  int sw = ((nl >> 3) & 7) << 4;

  f32x4 acc[8];
  #pragma unroll
  for (int i = 0; i < 8; ++i) acc[i] = (f32x4){0.f,0.f,0.f,0.f};

  const ushort* wrow = wT + l15*128;
  #pragma unroll
  for (int k0 = 0; k0 < 128; k0 += 32) {
    int kk = k0 + lhi*8;
    bf16x8 bfrag = *(const bf16x8*)&ldsB[nl*136 + (kk ^ sw)];
    #pragma unroll
    for (int mf = 0; mf < 8; ++mf) {
      bf16x8 afrag = *(const bf16x8*)(wrow + mf*16*128 + kk);
      acc[mf] = __builtin_amdgcn_mfma_f32_16x16x32_bf16(afrag, bfrag, acc[mf], 0, 0, 0);
    }
  }

  int n = n0 + nl;
  if (n < NPB) {
    uint s = (uint)n / 6u;
    int  u = n - 6*(int)s;
    const int TU1[6] = {0,1,2,4,5,8};
    const int TU2[6] = {0,3,6,4,7,8};
    int ta = TU1[u], tb = TU2[u];
    #pragma unroll
    for (int mf = 0; mf < 8; ++mf) {
      #pragma unroll
      for (int r = 0; r < 4; ++r) {
        int o = mf*16 + lhi*4 + r;
        size_t base = ((size_t)(b*COUT + o)*SSP + s)*9;
        float v = acc[mf][r];
        out[base + ta] = v;
        if (tb != ta) out[base + tb] = v;
      }
    }
  }
}

extern "C" void kernel_launch(void* const* d_in, const int* in_sizes, int n_in,
                              void* d_out, int out_size, void* d_ws, size_t ws_size,
                              hipStream_t stream) {
  const float* x = (const float*)d_in[0];
  const float* g = (const float*)d_in[1];
  float* out = (float*)d_out;

  float*  Gws    = (float*)d_ws;                          // 81 f32
  ushort* wT     = (ushort*)((char*)d_ws + 512);          // 128*128 bf16 = 32 KB
  ushort* folded = (ushort*)((char*)d_ws + 33280);        // 8*128*6976 bf16 ~= 14.25 MB

  prep_kernel<<<65, 256, 0, stream>>>(g, Gws, wT);
  fold_kernel<<<NB*CIN, 256, 0, stream>>>(x, Gws, folded);
  gemm_kernel<<<dim3(NPAD/64, NB), 256, 0, stream>>>(wT, folded, out);
}

// Round 2
// 138.108 us; speedup vs baseline: 2.9218x; 2.9218x over previous
//
#include <hip/hip_runtime.h>

#define NB    8
#define CIN   128
#define COUT  128
#define HH    32
#define WW    32
#define HO    34
#define WO    34
#define SSP   (HO*WO)     // 1156
#define SPAD  1160        // padded pixel count (8*145)
#define UU    6
#define NS    (SPAD*UU)   // 6960 = 145*48, N per (b,c)
#define NT    48          // GEMM N-tile = 8 pixels x 6 u
#define EPSC  1e-7f

typedef __attribute__((ext_vector_type(8))) short bf16x8;
typedef __attribute__((ext_vector_type(4))) float f32x4;

__device__ __forceinline__ ushort f2b(float f) {
  uint u = __float_as_uint(f);
  uint r = (u + 0x7fffu + ((u >> 16) & 1u)) >> 16;
  return (ushort)r;
}

// ---------------- prep: M_u[6][9][9] combined symmetric operators + wT[o][c]=bf16(g^2) ----
__global__ void prep_kernel(const float* __restrict__ g,
                            float* __restrict__ M,
                            ushort* __restrict__ wT) {
  if (blockIdx.x == 0) {
    __shared__ float Gs[81];
    int t = threadIdx.x;
    if (t < 9) {
      const int nums[9] = {0,1,2,3,0,5,6,7,1};
      float a = g[2*nums[t]];
      float c = g[2*nums[t]+1];
      float F[9], S2[9];
      if (t == 4) {
        F[0]=1;F[1]=0;F[2]=0;F[3]=0;F[4]=1;F[5]=0;F[6]=0;F[7]=0;F[8]=1;
        S2[0]=1;S2[1]=0;S2[2]=0;S2[3]=0;S2[4]=1;S2[5]=0;S2[6]=0;S2[7]=0;S2[8]=1;
      } else {
        F[0]=1.f; F[1]=-a;  F[2]=-a;
        F[3]=a;   F[4]=1.f; F[5]=-c;
        F[6]=a;   F[7]=c;   F[8]=1.f;
        S2[0]=1.f;  S2[1]=a;   S2[2]=a;
        S2[3]=-a;   S2[4]=1.f; S2[5]=c;
        S2[6]=-a;   S2[7]=-c;  S2[8]=1.f;
      }
      float det = F[0]*(F[4]*F[8]-F[5]*F[7]) - F[1]*(F[3]*F[8]-F[5]*F[6])
                + F[2]*(F[3]*F[7]-F[4]*F[6]) + EPSC;
      float inv[9];
      inv[0] = (F[4]*F[8]-F[5]*F[7]);
      inv[1] = (F[2]*F[7]-F[1]*F[8]);
      inv[2] = (F[1]*F[5]-F[2]*F[4]);
      inv[3] = (F[5]*F[6]-F[3]*F[8]);
      inv[4] = (F[0]*F[8]-F[2]*F[6]);
      inv[5] = (F[2]*F[3]-F[0]*F[5]);
      inv[6] = (F[3]*F[7]-F[4]*F[6]);
      inv[7] = (F[1]*F[6]-F[0]*F[7]);
      inv[8] = (F[0]*F[4]-F[1]*F[3]);
      float rd = 1.0f/det;
      #pragma unroll
      for (int i = 0; i < 9; ++i) inv[i] *= rd;
      #pragma unroll
      for (int i = 0; i < 3; ++i)
        #pragma unroll
        for (int j = 0; j < 3; ++j)
          Gs[t*9+i*3+j] = inv[i*3+0]*S2[0*3+j] + inv[i*3+1]*S2[1*3+j] + inv[i*3+2]*S2[2*3+j];
    }
    __syncthreads();
    if (t < 6) {
      const int T1[6] = {0,1,2,4,5,8};
      const int T2[6] = {0,3,6,4,7,8};
      int t1 = T1[t], t2 = T2[t];
      for (int co = 0; co < 9; ++co) {
        int i = co/3, j = co%3;
        for (int k = 0; k < 9; ++k) {
          int p = k/3, q = k%3;
          M[t*81 + co*9 + k] =
            0.5f*(Gs[t1*9+i*3+p]*Gs[t1*9+j*3+q] + Gs[t2*9+i*3+p]*Gs[t2*9+j*3+q]);
        }
      }
    }
  } else {
    int idx = (int)(blockIdx.x-1)*256 + threadIdx.x;   // idx = o*128 + c
    int o = idx >> 7, c = idx & 127;
    float w = g[16 + c*128 + o];
    wT[idx] = f2b(w*w);
  }
}

// ---------------- fold (gather, no atomics): per (b,c) block ----------------
// Per u-pass: transform all 1024 pixels y = M_u * x into LDS plane Y[px][9],
// then each output pixel (ho,wo) gathers its 9 bounds-checked neighbors.
__global__ __launch_bounds__(256) void fold_kernel(const float* __restrict__ x,
                                                   const float* __restrict__ M,
                                                   ushort* __restrict__ folded) {
  __shared__ float Y[1024*9];   // 36,864 B ; stride-9 -> conflict-free
  int tid = threadIdx.x;
  const float* xb = x + (size_t)blockIdx.x * (HH*WW*9);

  float X[4][9];
  #pragma unroll
  for (int kk = 0; kk < 4; ++kk) {
    int loc = tid + kk*256;
    #pragma unroll
    for (int i = 0; i < 9; ++i) X[kk][i] = xb[loc*9 + i];
  }

  size_t ob = (size_t)blockIdx.x * NS;

  for (int u = 0; u < 6; ++u) {
    if (u) __syncthreads();          // previous gather done before Y overwrite
    const float* Mu = M + u*81;      // wave-uniform -> scalar loads
    #pragma unroll
    for (int co = 0; co < 9; ++co) {
      float m[9];
      #pragma unroll
      for (int k = 0; k < 9; ++k) m[k] = Mu[co*9 + k];
      #pragma unroll
      for (int kk = 0; kk < 4; ++kk) {
        float y = m[0]*X[kk][0];
        #pragma unroll
        for (int k = 1; k < 9; ++k) y += m[k]*X[kk][k];
        Y[(tid + kk*256)*9 + co] = y;
      }
    }
    __syncthreads();

    #pragma unroll
    for (int r = 0; r < 5; ++r) {
      int idx = tid + r*256;          // output pixel s = ho*34+wo
      if (idx < SSP) {
        uint ho = (uint)idx / 34u;
        uint wo = (uint)idx - 34u*ho;
        float acc = 0.f;
        #pragma unroll
        for (int i = 0; i < 3; ++i) {
          int hh = (int)ho - i;
          bool okh = (uint)hh < 32u;
          #pragma unroll
          for (int j = 0; j < 3; ++j) {
            int wwj = (int)wo - j;
            bool ok = okh && ((uint)wwj < 32u);
            int px = hh*32 + wwj;
            px = min(max(px, 0), 1023);
            float v = Y[px*9 + i*3 + j];
            acc += ok ? v : 0.f;
          }
        }
        folded[ob + (size_t)idx*6 + u] = f2b(acc);
      }
    }
  }
}

// ---------------- gemm: C[o][n] = sum_c wT[o][c]*folded[b][c][n]; n = s*6+u ----
// N-tile = 48 = 8 pixels x 6 u -> epilogue assembles full 36B pixels, coalesced.
__global__ __launch_bounds__(192) void gemm_kernel(const ushort* __restrict__ wT,
                                                   const ushort* __restrict__ folded,
                                                   float* __restrict__ out) {
  __shared__ __align__(16) char smem[128*52*4];   // 26,624 B (ldsB and ldsC alias)
  ushort* ldsB = (ushort*)smem;                   // [48][136] swizzled
  float*  ldsC = (float*)smem;                    // [128][52]

  int tid  = threadIdx.x;
  int b    = blockIdx.y;
  int tile = blockIdx.x;
  int n0   = tile * NT;

  // stage B panel [48 n][128 k], transpose + XOR swizzle
  #pragma unroll
  for (int p = 0; p < 4; ++p) {
    int chunk = tid + p*192;              // 0..767 ; c = chunk/6, nc = (chunk%6)*8
    int c  = chunk / 6;
    int nc = (chunk - 6*c) * 8;
    const ushort* src = folded + ((size_t)(b*CIN + c)*NS + n0 + nc);
    uint4 v = *(const uint4*)src;
    ushort e[8];
    e[0]=(ushort)(v.x & 0xffffu); e[1]=(ushort)(v.x >> 16);
    e[2]=(ushort)(v.y & 0xffffu); e[3]=(ushort)(v.y >> 16);
    e[4]=(ushort)(v.z & 0xffffu); e[5]=(ushort)(v.z >> 16);
    e[6]=(ushort)(v.w & 0xffffu); e[7]=(ushort)(v.w >> 16);
    #pragma unroll
    for (int j = 0; j < 8; ++j) {
      int nl  = nc + j;
      int ksw = c ^ (((nl >> 3) & 7) << 4);
      ldsB[nl*136 + ksw] = e[j];
    }
  }
  __syncthreads();

  int wave = tid >> 6, lane = tid & 63;
  int l15 = lane & 15, lhi = lane >> 4;
  int nl = wave*16 + l15;                 // 0..47
  int sw = ((nl >> 3) & 7) << 4;

  f32x4 acc[8];
  #pragma unroll
  for (int i = 0; i < 8; ++i) acc[i] = (f32x4){0.f,0.f,0.f,0.f};

  const ushort* wrow = wT + l15*128;
  #pragma unroll
  for (int k0 = 0; k0 < 128; k0 += 32) {
    int kk = k0 + lhi*8;
    bf16x8 bfrag = *(const bf16x8*)&ldsB[nl*136 + (kk ^ sw)];
    #pragma unroll
    for (int mf = 0; mf < 8; ++mf) {
      bf16x8 afrag = *(const bf16x8*)(wrow + mf*16*128 + kk);
      acc[mf] = __builtin_amdgcn_mfma_f32_16x16x32_bf16(afrag, bfrag, acc[mf], 0, 0, 0);
    }
  }

  __syncthreads();   // done reading ldsB
  #pragma unroll
  for (int mf = 0; mf < 8; ++mf)
    #pragma unroll
    for (int r = 0; r < 4; ++r) {
      int o = mf*16 + lhi*4 + r;
      ldsC[o*52 + nl] = acc[mf][r];       // 2-way bank alias only
    }
  __syncthreads();

  // write: one (o, s) pixel per thread-iter -> 9 contiguous f32 (36 B)
  int s0 = tile * 8;
  const int umap[9] = {0,1,2,1,3,4,2,4,5};
  #pragma unroll
  for (int r = 0; r < 6; ++r) {
    int pair = tid + r*192;
    if (pair < 1024) {
      int o  = pair >> 3;
      int sl = pair & 7;
      int s  = s0 + sl;
      if (s < SSP) {
        float v[6];
        #pragma unroll
        for (int u = 0; u < 6; ++u) v[u] = ldsC[o*52 + sl*6 + u];
        size_t base = ((size_t)(b*COUT + o)*SSP + s)*9;
        #pragma unroll
        for (int t = 0; t < 9; ++t) out[base + t] = v[umap[t]];
      }
    }
  }
}

extern "C" void kernel_launch(void* const* d_in, const int* in_sizes, int n_in,
                              void* d_out, int out_size, void* d_ws, size_t ws_size,
                              hipStream_t stream) {
  const float* x = (const float*)d_in[0];
  const float* g = (const float*)d_in[1];
  float* out = (float*)d_out;

  float*  M      = (float*)d_ws;                          // 486 f32 = 1944 B
  ushort* wT     = (ushort*)((char*)d_ws + 4096);         // 128*128 bf16 = 32 KB
  ushort* folded = (ushort*)((char*)d_ws + 4096 + 32768); // 8*128*6960 bf16 = 14.25 MB

  prep_kernel<<<65, 256, 0, stream>>>(g, M, wT);
  fold_kernel<<<NB*CIN, 256, 0, stream>>>(x, M, folded);
  gemm_kernel<<<dim3(NS/NT, NB), 192, 0, stream>>>(wT, folded, out);
}